// Round 2
// baseline (184.134 us; speedup 1.0000x reference)
//
#include <hip/hip_runtime.h>

#define BATCH 8
#define NH 6
#define HEAD_DIM 32
#define CCH 192
#define HH 56
#define WW 56
#define HWSZ (HH * WW)          // 3136
#define PH 60
#define PW 60
#define PPLANE (PH * PW)        // 3600
#define KPOS 9
#define SCALE 0.17677669529663687f  // 32^-0.5

// ---------------------------------------------------------------------------
// Kernel 1: repack k/v from [BH, 32, 56, 56] (channel-major) into zero-padded
// channel-last [BH, 60, 60, 32]. One block per (tensor, bh, yy). LDS tile
// transpose: coalesced global read (lanes along x), conflict-free LDS
// (stride 57), coalesced global write (lanes along d).
// ---------------------------------------------------------------------------
__global__ __launch_bounds__(256) void repack_kernel(
    const float* __restrict__ k, const float* __restrict__ v,
    float* __restrict__ kp, float* __restrict__ vp)
{
    __shared__ float lds[HEAD_DIM * 57];

    int yy = blockIdx.x % PH;          // padded row 0..59
    int bh = blockIdx.x / PH;          // 0..47
    const float* src = (blockIdx.y == 0) ? k : v;
    float*       dst = (blockIdx.y == 0) ? kp : vp;

    int t = threadIdx.x;
    bool interior_row = (yy >= 2) && (yy < 58);

    if (interior_row) {
        int y = yy - 2;
        const float* s = src + (size_t)bh * (HEAD_DIM * HWSZ) + y * WW;
#pragma unroll
        for (int i = 0; i < 7; i++) {          // 7*256 = 1792 = 32*56 exactly
            int idx = t + i * 256;
            int d = idx / WW;
            int x = idx - d * WW;
            lds[d * 57 + x] = s[d * HWSZ + x];
        }
    }
    __syncthreads();

    float* drow = dst + ((size_t)bh * PPLANE + (size_t)yy * PW) * HEAD_DIM;
#pragma unroll
    for (int i = 0; i < 8; i++) {              // covers 60*32 = 1920
        int idx = t + i * 256;
        if (idx < PW * HEAD_DIM) {
            int xx = idx >> 5;                 // 0..59
            int d  = idx & 31;
            float val = 0.0f;
            if (interior_row && xx >= 2 && xx < 58)
                val = lds[d * 57 + (xx - 2)];
            drow[idx] = val;
        }
    }
}

// ---------------------------------------------------------------------------
// Kernel 2: per-thread (b, h, y, x). All k/v accesses are contiguous 128-B
// blocks (8x float4), branch-free (padding pre-baked as zeros).
// ---------------------------------------------------------------------------
__global__ __launch_bounds__(256) void dilate_attn_main(
    const float* __restrict__ q,
    const float* __restrict__ kp,
    const float* __restrict__ vp,
    float* __restrict__ out)
{
    int tid = blockIdx.x * 256 + threadIdx.x;   // grid exactly covers 150528
    int x  = tid % WW;
    int y  = (tid / WW) % HH;
    int bh = tid / HWSZ;                        // b*NH + h

    // ---- load q[d] (coalesced scalar loads across lanes) ----
    const float* qb = q + (size_t)bh * (HEAD_DIM * HWSZ) + y * WW + x;
    float qreg[HEAD_DIM];
#pragma unroll
    for (int d = 0; d < HEAD_DIM; d++) qreg[d] = qb[d * HWSZ];

    // ---- 9 tap base offsets in the padded channel-last layout ----
    int tap[KPOS];
#pragma unroll
    for (int kk = 0; kk < KPOS; kk++) {
        int iy = kk / 3, ix = kk % 3;
        // padded coords: yy = (y+2) + 2*(iy-1) = y + 2*iy ; xx = x + 2*ix
        tap[kk] = (bh * PPLANE + (y + 2 * iy) * PW + (x + 2 * ix)) * HEAD_DIM;
    }

    // ---- QK^T ----
    float attn[KPOS];
#pragma unroll
    for (int kk = 0; kk < KPOS; kk++) {
        const float4* kt = reinterpret_cast<const float4*>(kp + tap[kk]);
        float acc = 0.0f;
#pragma unroll
        for (int j = 0; j < 8; j++) {
            float4 kv = kt[j];
            acc = fmaf(qreg[4 * j + 0], kv.x, acc);
            acc = fmaf(qreg[4 * j + 1], kv.y, acc);
            acc = fmaf(qreg[4 * j + 2], kv.z, acc);
            acc = fmaf(qreg[4 * j + 3], kv.w, acc);
        }
        attn[kk] = acc * SCALE;
    }

    // ---- softmax over 9 taps (OOB taps contribute logit 0 via zero k) ----
    float m = attn[0];
#pragma unroll
    for (int kk = 1; kk < KPOS; kk++) m = fmaxf(m, attn[kk]);
    float s = 0.0f;
#pragma unroll
    for (int kk = 0; kk < KPOS; kk++) {
        attn[kk] = __expf(attn[kk] - m);
        s += attn[kk];
    }
    float inv = 1.0f / s;
#pragma unroll
    for (int kk = 0; kk < KPOS; kk++) attn[kk] *= inv;

    // ---- PV ----
    float4 acc[8];
#pragma unroll
    for (int j = 0; j < 8; j++) acc[j] = make_float4(0.f, 0.f, 0.f, 0.f);

#pragma unroll
    for (int kk = 0; kk < KPOS; kk++) {
        const float4* vt = reinterpret_cast<const float4*>(vp + tap[kk]);
        float a = attn[kk];
#pragma unroll
        for (int j = 0; j < 8; j++) {
            float4 vv = vt[j];
            acc[j].x = fmaf(a, vv.x, acc[j].x);
            acc[j].y = fmaf(a, vv.y, acc[j].y);
            acc[j].z = fmaf(a, vv.z, acc[j].z);
            acc[j].w = fmaf(a, vv.w, acc[j].w);
        }
    }

    // ---- store: out[b, y, x, h*32 + d] — 32 contiguous floats ----
    int h = bh % NH;
    int b = bh / NH;
    float* ob = out + ((size_t)((b * HH + y) * WW + x)) * CCH + h * HEAD_DIM;
    float4* ob4 = reinterpret_cast<float4*>(ob);
#pragma unroll
    for (int j = 0; j < 8; j++) ob4[j] = acc[j];
}

extern "C" void kernel_launch(void* const* d_in, const int* in_sizes, int n_in,
                              void* d_out, int out_size, void* d_ws, size_t ws_size,
                              hipStream_t stream) {
    const float* q = (const float*)d_in[0];
    const float* k = (const float*)d_in[1];
    const float* v = (const float*)d_in[2];
    float* out = (float*)d_out;

    // workspace: kp then vp, each BATCH*NH * 60*60 * 32 floats = 22.1 MB
    const size_t plane_elems = (size_t)BATCH * NH * PPLANE * HEAD_DIM; // 5,529,600
    float* kp = (float*)d_ws;
    float* vp = kp + plane_elems;

    dim3 rgrid(BATCH * NH * PH, 2);   // 2880 x 2 blocks
    repack_kernel<<<rgrid, 256, 0, stream>>>(k, v, kp, vp);

    const int total = BATCH * NH * HWSZ;          // 150528 = 588 * 256
    dilate_attn_main<<<total / 256, 256, 0, stream>>>(q, kp, vp, out);
}

// Round 3
// 123.894 us; speedup vs baseline: 1.4862x; 1.4862x over previous
//
#include <hip/hip_runtime.h>

#define NH 6
#define HEAD_DIM 32
#define CCH 192
#define HH 56
#define WW 56
#define HWSZ (HH * WW)            // 3136
#define KPOS 9
#define SCALE 0.17677669529663687f  // 32^-0.5
#define PXB 64                    // pixels per block

// Fused dilated attention:
//  stage 1: threads (pixel, iy) iy=0..2 -> 3 logits each, into LDS
//  stage 2: threads (pixel, dq) dq=0..3 -> softmax (redundant) + PV for 8 dims
// All global loads channel-major => lanes walk x => fully coalesced.
__global__ __launch_bounds__(256) void dilate_attn_fused(
    const float* __restrict__ q,
    const float* __restrict__ k,
    const float* __restrict__ v,
    float* __restrict__ out)
{
    __shared__ float sattn[PXB * 13];   // stride 13: conflict-free
    const int t = threadIdx.x;

    // ---------------- stage 1: QK^T ----------------
    {
        const int iy = t >> 6;          // wave id 0..3
        const int pl = t & 63;
        if (iy < 3) {
            const int gp = blockIdx.x * PXB + pl;
            const int x  = gp % WW;
            const int y  = (gp / WW) % HH;
            const int bh = gp / HWSZ;
            const int yy = y + 2 * iy - 2;

            float a0 = 0.f, a1 = 0.f, a2 = 0.f;
            if (yy >= 0 && yy < HH) {
                const float* qb = q + (size_t)bh * (HEAD_DIM * HWSZ) + y * WW + x;
                const float* kb = k + (size_t)bh * (HEAD_DIM * HWSZ) + yy * WW;
                const bool ok0 = (x - 2) >= 0;
                const bool ok2 = (x + 2) < WW;
                const int  o0  = ok0 ? (x - 2) : 0;   // clamped, mask result later
                const int  o1  = x;
                const int  o2  = ok2 ? (x + 2) : 0;
#pragma unroll
                for (int d = 0; d < HEAD_DIM; d++) {
                    const float qd = qb[d * HWSZ];
                    const float* kd = kb + d * HWSZ;
                    a0 = fmaf(qd, kd[o0], a0);
                    a1 = fmaf(qd, kd[o1], a1);
                    a2 = fmaf(qd, kd[o2], a2);
                }
                if (!ok0) a0 = 0.f;     // OOB tap: zero-padded k => logit 0
                if (!ok2) a2 = 0.f;
            }
            sattn[pl * 13 + iy * 3 + 0] = a0 * SCALE;
            sattn[pl * 13 + iy * 3 + 1] = a1 * SCALE;
            sattn[pl * 13 + iy * 3 + 2] = a2 * SCALE;
        }
    }

    __syncthreads();

    // ---------------- stage 2: softmax + PV ----------------
    {
        const int pl = t >> 2;
        const int dq = t & 3;           // d-octet 0..3
        const int gp = blockIdx.x * PXB + pl;
        const int x  = gp % WW;
        const int y  = (gp / WW) % HH;
        const int bh = gp / HWSZ;

        float a[KPOS];
#pragma unroll
        for (int kk = 0; kk < KPOS; kk++) a[kk] = sattn[pl * 13 + kk];

        float m = a[0];
#pragma unroll
        for (int kk = 1; kk < KPOS; kk++) m = fmaxf(m, a[kk]);
        float s = 0.f;
#pragma unroll
        for (int kk = 0; kk < KPOS; kk++) {
            a[kk] = __expf(a[kk] - m);
            s += a[kk];
        }
        const float inv = 1.f / s;

        const float* vb = v + (size_t)bh * (HEAD_DIM * HWSZ) + (size_t)dq * 8 * HWSZ;

        float acc[8];
#pragma unroll
        for (int j = 0; j < 8; j++) acc[j] = 0.f;

#pragma unroll
        for (int kk = 0; kk < KPOS; kk++) {
            const int yy = y + 2 * (kk / 3) - 2;
            const int xx = x + 2 * (kk % 3) - 2;
            const bool ok = (yy >= 0) & (yy < HH) & (xx >= 0) & (xx < WW);
            const int off = ok ? (yy * WW + xx) : 0;   // clamped address
            const float w = ok ? (a[kk] * inv) : 0.f;  // zero weight for OOB v
            const float* vp = vb + off;
#pragma unroll
            for (int j = 0; j < 8; j++)
                acc[j] = fmaf(w, vp[j * HWSZ], acc[j]);
        }

        // store: lane-quad (dq 0..3, same pixel) covers one full 128-B line
        const int h = bh % NH;
        const int b = bh / NH;
        float* ob = out + ((size_t)((b * HH + y) * WW + x)) * CCH
                        + h * HEAD_DIM + dq * 8;
        float4 r0 = make_float4(acc[0], acc[1], acc[2], acc[3]);
        float4 r1 = make_float4(acc[4], acc[5], acc[6], acc[7]);
        reinterpret_cast<float4*>(ob)[0] = r0;
        reinterpret_cast<float4*>(ob)[1] = r1;
    }
}

extern "C" void kernel_launch(void* const* d_in, const int* in_sizes, int n_in,
                              void* d_out, int out_size, void* d_ws, size_t ws_size,
                              hipStream_t stream) {
    const float* q = (const float*)d_in[0];
    const float* k = (const float*)d_in[1];
    const float* v = (const float*)d_in[2];
    float* out = (float*)d_out;

    const int total_px = 8 * NH * HWSZ;        // 150528
    const int blocks = total_px / PXB;         // 2352
    dilate_attn_fused<<<blocks, 256, 0, stream>>>(q, k, v, out);
}